// Round 9
// baseline (1773.735 us; speedup 1.0000x reference)
//
#include <hip/hip_runtime.h>

// Problem constants
#define NB 2
#define CC 512
#define NN 2304
#define NH 8
#define DD 16
#define TT 128          // NH*DD
#define O3 384          // 3*TT
#define NBLK 1152u      // mega-kernel grid size

typedef __attribute__((ext_vector_type(4))) float f32x4;
typedef __attribute__((ext_vector_type(8))) __bf16 bf16x8;
typedef __attribute__((ext_vector_type(4))) __bf16 bf16x4;
typedef __attribute__((ext_vector_type(4))) _Float16 f16x4;

// ---------------------------------------------------------------------------
// Grid barrier: agent-scope arrival counter per sync point. Counters are
// zeroed by a hipMemsetAsync before launch (never trust ws poison).
// Co-residency is guaranteed by __launch_bounds__(256,5): 5 blocks/CU x 256
// CUs = 1280 >= 1152 grid. threadfence before arrival publishes this block's
// writes device-wide; acquire load + threadfence after makes them visible.
// ---------------------------------------------------------------------------
__device__ __forceinline__ void gridbar(unsigned* bar, int slot) {
    __threadfence();
    __syncthreads();
    if (threadIdx.x == 0) {
        __hip_atomic_fetch_add(bar + slot, 1u, __ATOMIC_RELEASE,
                               __HIP_MEMORY_SCOPE_AGENT);
        while (__hip_atomic_load(bar + slot, __ATOMIC_ACQUIRE,
                                 __HIP_MEMORY_SCOPE_AGENT) < NBLK)
            __builtin_amdgcn_s_sleep(8);
    }
    __syncthreads();
    __threadfence();
}

// ---------------------------------------------------------------------------
// MEGA-KERNEL: all 6 stages (R8-proven bodies) with 5 grid barriers.
// Stage widths: k0=640, k1=864, k2=576 (4 splits x 576 keys), k2c=144,
// k3=1152, k4=512. Idle blocks skip straight to the barrier.
// ---------------------------------------------------------------------------
__global__ __launch_bounds__(256, 5) void mega(
    const float* __restrict__ x, const float* __restrict__ wqkv,
    const float* __restrict__ temp, const float* __restrict__ wout,
    const float* __restrict__ gamma, const float* __restrict__ beta,
    float* out,
    __bf16* __restrict__ xT, __bf16* __restrict__ wqb, __bf16* __restrict__ wob,
    _Float16* __restrict__ Q, _Float16* __restrict__ K, _Float16* __restrict__ VT,
    __bf16* __restrict__ AO, float* __restrict__ Opart, float* __restrict__ Lpart,
    unsigned* bar)
{
    const int bid = blockIdx.x;
    const int t = threadIdx.x;
    const int lane = t & 63, wave = t >> 6;
    const int quad = lane >> 4, col = lane & 15;

    __shared__ float tile[64][65];          // stage 0 (16.6 KB; 5x fits 160KB)
    __shared__ float rs[4], rq[4];          // stage 5

    // ============ stage 0: x transpose fp32->bf16 + weight conversion ======
    if (bid < 576) {
        int b = bid / 288, rem = bid % 288;
        int nt = rem / 8, cb = rem % 8;
        int n0 = nt * 64, c0 = cb * 64;
        int tc = t >> 6, tn = t & 63;
#pragma unroll
        for (int i = 0; i < 16; i++) {
            int cl = i * 4 + tc;
            tile[cl][tn] = x[(size_t)(b * CC + c0 + cl) * NN + n0 + tn];
        }
        __syncthreads();
#pragma unroll
        for (int i = 0; i < 16; i++) {
            int nl = i * 4 + tc;
            xT[(size_t)(b * NN + n0 + nl) * CC + c0 + tn] = (__bf16)tile[tn][nl];
        }
    } else if (bid < 640) {
        int wid = bid - 576;
        int base = wid * 256 + t;
#pragma unroll
        for (int i = 0; i < 16; i++) {
            int j = base + i * 16384;
            if (j < O3 * CC) wqb[j] = (__bf16)wqkv[j];
            else             wob[j - O3 * CC] = (__bf16)wout[j - O3 * CC];
        }
    }
    gridbar(bar, 0);

    // ============ stage 1: QKV GEMM + fused L2 norm (fp16 out) =============
    if (bid < 864) {
        int ob = bid % 12, nt = (bid / 12) % 36, b = bid / 432;
        int n0 = nt * 64 + wave * 16;
        int o0 = ob * 32;

        f32x4 acc0 = {0.f,0.f,0.f,0.f}, acc1 = {0.f,0.f,0.f,0.f};
        const __bf16* arow  = xT + (size_t)(b * NN + n0 + col) * CC + quad * 8;
        const __bf16* brow0 = wqb + (size_t)(o0 + col) * CC + quad * 8;
        const __bf16* brow1 = brow0 + 16 * CC;

        bf16x8 a  = *(const bf16x8*)(arow);
        bf16x8 w0 = *(const bf16x8*)(brow0);
        bf16x8 w1 = *(const bf16x8*)(brow1);
#pragma unroll
        for (int ks = 0; ks < 16; ks++) {
            bf16x8 an, wn0, wn1;
            if (ks < 15) {
                an  = *(const bf16x8*)(arow + (ks + 1) * 32);
                wn0 = *(const bf16x8*)(brow0 + (ks + 1) * 32);
                wn1 = *(const bf16x8*)(brow1 + (ks + 1) * 32);
            }
            acc0 = __builtin_amdgcn_mfma_f32_16x16x32_bf16(a, w0, acc0, 0, 0, 0);
            acc1 = __builtin_amdgcn_mfma_f32_16x16x32_bf16(a, w1, acc1, 0, 0, 0);
            a = an; w0 = wn0; w1 = wn1;
        }
#pragma unroll
        for (int s = 0; s < 2; s++) {
            f32x4 v = s ? acc1 : acc0;
            int oc = o0 + s * 16 + col;
            int d = oc & 15, h = (oc >> 4) & 7, kind = oc >> 7;
            if (kind < 2) {
                float ss0 = v[0]*v[0], ss1 = v[1]*v[1], ss2 = v[2]*v[2], ss3 = v[3]*v[3];
#pragma unroll
                for (int m = 1; m < 16; m <<= 1) {
                    ss0 += __shfl_xor(ss0, m);
                    ss1 += __shfl_xor(ss1, m);
                    ss2 += __shfl_xor(ss2, m);
                    ss3 += __shfl_xor(ss3, m);
                }
                v[0] *= 1.0f / fmaxf(sqrtf(ss0), 1e-12f);
                v[1] *= 1.0f / fmaxf(sqrtf(ss1), 1e-12f);
                v[2] *= 1.0f / fmaxf(sqrtf(ss2), 1e-12f);
                v[3] *= 1.0f / fmaxf(sqrtf(ss3), 1e-12f);
                _Float16* dst = (kind == 0 ? Q : K) + (size_t)(b * NH + h) * NN * DD;
#pragma unroll
                for (int r = 0; r < 4; r++)
                    dst[(size_t)(n0 + quad * 4 + r) * DD + d] = (_Float16)v[r];
            } else {
                f16x4 pk;
#pragma unroll
                for (int r = 0; r < 4; r++) pk[r] = (_Float16)v[r];
                *(f16x4*)(VT + (size_t)((b * NH + h) * DD + d) * NN + n0 + quad * 4) = pk;
            }
        }
    }
    gridbar(bar, 1);

    // ============ stage 2: attention (transpose-free, 4x q-block, split=4) ==
    if (bid < 576) {
        int qt = bid % 9, bh = (bid / 9) % 16, sp = bid / 144;
        int kbase = sp * 576;                // 4 splits x 576 keys = 18 groups of 32
        int qbase = qt * 256 + wave * 64;

        const _Float16* Qb = Q + (size_t)bh * NN * DD;
        float tl2 = temp[bh & 7] * 1.4426950408889634f;

        f16x4 qf0 = *(const f16x4*)(Qb + (size_t)(qbase +  0 + col) * DD + quad * 4);
        f16x4 qf1 = *(const f16x4*)(Qb + (size_t)(qbase + 16 + col) * DD + quad * 4);
        f16x4 qf2 = *(const f16x4*)(Qb + (size_t)(qbase + 32 + col) * DD + quad * 4);
        f16x4 qf3 = *(const f16x4*)(Qb + (size_t)(qbase + 48 + col) * DD + quad * 4);

        f32x4 oa0 = {0.f,0.f,0.f,0.f}, oa1 = {0.f,0.f,0.f,0.f};
        f32x4 oa2 = {0.f,0.f,0.f,0.f}, oa3 = {0.f,0.f,0.f,0.f};
        float la0 = 0.f, la1 = 0.f, la2 = 0.f, la3 = 0.f;
        const f32x4 zc = {0.f,0.f,0.f,0.f};

        const _Float16* kp = K + (size_t)bh * NN * DD + (size_t)(kbase + col) * DD + quad * 4;
        const _Float16* vp = VT + (size_t)bh * DD * NN + (size_t)col * NN + kbase + quad * 4;

        f16x4 kfa = *(const f16x4*)(kp);
        f16x4 kfb = *(const f16x4*)(kp + 16 * DD);
        f16x4 vfa = *(const f16x4*)(vp);
        f16x4 vfb = *(const f16x4*)(vp + 16);

#define K2_CHUNK(KF, VF)                                                        \
    {                                                                           \
        f32x4 s0 = __builtin_amdgcn_mfma_f32_16x16x16f16(KF, qf0, zc, 0, 0, 0); \
        f32x4 s1 = __builtin_amdgcn_mfma_f32_16x16x16f16(KF, qf1, zc, 0, 0, 0); \
        f32x4 s2 = __builtin_amdgcn_mfma_f32_16x16x16f16(KF, qf2, zc, 0, 0, 0); \
        f32x4 s3 = __builtin_amdgcn_mfma_f32_16x16x16f16(KF, qf3, zc, 0, 0, 0); \
        f16x4 p0, p1, p2, p3;                                                   \
        _Pragma("unroll")                                                       \
        for (int r = 0; r < 4; ++r) {                                           \
            float e0 = __builtin_amdgcn_exp2f(tl2 * s0[r]);                     \
            float e1 = __builtin_amdgcn_exp2f(tl2 * s1[r]);                     \
            float e2 = __builtin_amdgcn_exp2f(tl2 * s2[r]);                     \
            float e3 = __builtin_amdgcn_exp2f(tl2 * s3[r]);                     \
            p0[r] = (_Float16)e0; la0 += e0;                                    \
            p1[r] = (_Float16)e1; la1 += e1;                                    \
            p2[r] = (_Float16)e2; la2 += e2;                                    \
            p3[r] = (_Float16)e3; la3 += e3;                                    \
        }                                                                       \
        oa0 = __builtin_amdgcn_mfma_f32_16x16x16f16(VF, p0, oa0, 0, 0, 0);      \
        oa1 = __builtin_amdgcn_mfma_f32_16x16x16f16(VF, p1, oa1, 0, 0, 0);      \
        oa2 = __builtin_amdgcn_mfma_f32_16x16x16f16(VF, p2, oa2, 0, 0, 0);      \
        oa3 = __builtin_amdgcn_mfma_f32_16x16x16f16(VF, p3, oa3, 0, 0, 0);      \
    }

        for (int g = 0; g < 18; ++g) {       // 18 groups x 32 keys = 576
            f16x4 kna, knb, vna, vnb;
            if (g < 17) {
                kna = *(const f16x4*)(kp + 32 * DD);
                knb = *(const f16x4*)(kp + 48 * DD);
                vna = *(const f16x4*)(vp + 32);
                vnb = *(const f16x4*)(vp + 48);
            }
            K2_CHUNK(kfa, vfa)
            K2_CHUNK(kfb, vfb)
            kfa = kna; kfb = knb; vfa = vna; vfb = vnb;
            kp += 32 * DD; vp += 32;
        }
#undef K2_CHUNK

        la0 += __shfl_xor(la0, 16); la0 += __shfl_xor(la0, 32);
        la1 += __shfl_xor(la1, 16); la1 += __shfl_xor(la1, 32);
        la2 += __shfl_xor(la2, 16); la2 += __shfl_xor(la2, 32);
        la3 += __shfl_xor(la3, 16); la3 += __shfl_xor(la3, 32);

        float* Ob = Opart + (((size_t)sp * 16 + bh) * DD + quad * 4) * NN + qbase + col;
#pragma unroll
        for (int r = 0; r < 4; ++r) {
            Ob[(size_t)r * NN +  0] = oa0[r];
            Ob[(size_t)r * NN + 16] = oa1[r];
            Ob[(size_t)r * NN + 32] = oa2[r];
            Ob[(size_t)r * NN + 48] = oa3[r];
        }
        float lv = (quad == 0) ? la0 : (quad == 1) ? la1 : (quad == 2) ? la2 : la3;
        Lpart[((size_t)sp * 16 + bh) * NN + qbase + quad * 16 + col] = lv;
    }
    gridbar(bar, 2);

    // ============ stage 3: combine 4 splits + divide -> AO ==================
    if (bid < 144) {
        int gid = bid * 256 + t;             // 0..36863
        int bh = gid / NN, n = gid % NN;
        int b = bh >> 3, h = bh & 7;
        float l = 0.f;
#pragma unroll
        for (int sp = 0; sp < 4; sp++)
            l += Lpart[((size_t)sp * 16 + bh) * NN + n];
        float inv = 1.0f / l;
        float o[16];
#pragma unroll
        for (int d = 0; d < 16; d++) o[d] = 0.f;
#pragma unroll
        for (int sp = 0; sp < 4; sp++) {
            const float* Ob = Opart + ((size_t)sp * 16 + bh) * DD * NN + n;
#pragma unroll
            for (int d = 0; d < 16; d++) o[d] += Ob[(size_t)d * NN];
        }
        bf16x8 v0, v1;
#pragma unroll
        for (int d = 0; d < 8; d++) v0[d] = (__bf16)(o[d] * inv);
#pragma unroll
        for (int d = 0; d < 8; d++) v1[d] = (__bf16)(o[d + 8] * inv);
        __bf16* dst = AO + (size_t)b * NN * TT + (size_t)n * TT + h * DD;
        *(bf16x8*)dst = v0;
        *(bf16x8*)(dst + 8) = v1;
    }
    gridbar(bar, 3);

    // ============ stage 4: projection -> pre-BN fp32 in d_out ==============
    {
        int cb = bid % 16, nt = (bid / 16) % 36, b = bid / 576;
        int n0 = nt * 64 + wave * 16, c0 = cb * 32;

        f32x4 acc0 = {0.f,0.f,0.f,0.f}, acc1 = {0.f,0.f,0.f,0.f};
        const __bf16* ab  = AO + (size_t)(b * NN + n0 + col) * TT + quad * 8;
        const __bf16* wb0 = wob + (size_t)(c0 + col) * TT + quad * 8;
        const __bf16* wb1 = wb0 + 16 * TT;
#pragma unroll
        for (int ks = 0; ks < 4; ks++) {
            bf16x8 a  = *(const bf16x8*)(ab + ks * 32);
            bf16x8 w0 = *(const bf16x8*)(wb0 + ks * 32);
            bf16x8 w1 = *(const bf16x8*)(wb1 + ks * 32);
            acc0 = __builtin_amdgcn_mfma_f32_16x16x32_bf16(a, w0, acc0, 0, 0, 0);
            acc1 = __builtin_amdgcn_mfma_f32_16x16x32_bf16(a, w1, acc1, 0, 0, 0);
        }
#pragma unroll
        for (int s = 0; s < 2; s++) {
            int c = c0 + s * 16 + col;
            float* dst = out + (size_t)(b * CC + c) * NN + n0 + quad * 4;
            *(f32x4*)dst = s ? acc1 : acc0;
        }
    }
    gridbar(bar, 4);

    // ============ stage 5: training-mode BatchNorm in place =================
    if (bid < 512) {
        int c = bid;
        float vals[18];
        float s = 0.f, q = 0.f;
#pragma unroll
        for (int i = 0; i < 18; i++) {
            int j = i * 256 + t;
            int b = j / NN, n = j % NN;
            float v = out[(size_t)(b * CC + c) * NN + n];
            vals[i] = v; s += v; q += v * v;
        }
#pragma unroll
        for (int m = 1; m < 64; m <<= 1) { s += __shfl_xor(s, m); q += __shfl_xor(q, m); }
        if (lane == 0) { rs[wave] = s; rq[wave] = q; }
        __syncthreads();
        s = rs[0] + rs[1] + rs[2] + rs[3];
        q = rq[0] + rq[1] + rq[2] + rq[3];
        float mean = s * (1.0f / 4608.0f);
        float var = q * (1.0f / 4608.0f) - mean * mean;
        float sc = rsqrtf(var + 1e-5f) * gamma[c];
        float sh = beta[c] - mean * sc;
#pragma unroll
        for (int i = 0; i < 18; i++) {
            int j = i * 256 + t;
            int b = j / NN, n = j % NN;
            out[(size_t)(b * CC + c) * NN + n] = vals[i] * sc + sh;
        }
    }
}

// ---------------------------------------------------------------------------
extern "C" void kernel_launch(void* const* d_in, const int* in_sizes, int n_in,
                              void* d_out, int out_size, void* d_ws, size_t ws_size,
                              hipStream_t stream) {
    const float* x     = (const float*)d_in[0];
    const float* wqkv  = (const float*)d_in[1];
    const float* temp  = (const float*)d_in[2];
    const float* wout  = (const float*)d_in[3];
    const float* gamma = (const float*)d_in[4];
    const float* beta  = (const float*)d_in[5];
    float* out = (float*)d_out;

    char* ws = (char*)d_ws;
    const size_t OFF_XT  = 0;                 // 2*2304*512*2   = 4,718,592
    const size_t OFF_WQ  = 4718592;           // 384*512*2      =   393,216
    const size_t OFF_WO  = 5111808;           // 512*128*2      =   131,072
    const size_t OFF_Q   = 5242880;           // 2*8*2304*16*2  = 1,179,648
    const size_t OFF_K   = 6422528;
    const size_t OFF_VT  = 7602176;
    const size_t OFF_AO  = 8781824;           // 2*2304*128*2   = 1,179,648 -> 9,961,472
    const size_t OFF_OP  = 9961472;           // 4*16*16*2304*4 = 9,437,184 -> 19,398,656
    const size_t OFF_LP  = 19398656;          // 4*16*2304*4    =   589,824 -> 19,988,480
    const size_t OFF_BAR = 19988480;          // 64 B barrier counters

    __bf16* xT  = (__bf16*)(ws + OFF_XT);
    __bf16* wqb = (__bf16*)(ws + OFF_WQ);
    __bf16* wob = (__bf16*)(ws + OFF_WO);
    _Float16* Q  = (_Float16*)(ws + OFF_Q);
    _Float16* K  = (_Float16*)(ws + OFF_K);
    _Float16* VT = (_Float16*)(ws + OFF_VT);
    __bf16* AO  = (__bf16*)(ws + OFF_AO);
    float* Opart = (float*)(ws + OFF_OP);
    float* Lpart = (float*)(ws + OFF_LP);
    unsigned* bar = (unsigned*)(ws + OFF_BAR);

    hipMemsetAsync(ws + OFF_BAR, 0, 64, stream);   // zero barrier counters
    mega<<<NBLK, 256, 0, stream>>>(x, wqkv, temp, wout, gamma, beta, out,
                                   xT, wqb, wob, Q, K, VT, AO, Opart, Lpart, bar);
}

// Round 10
// 990.699 us; speedup vs baseline: 1.7904x; 1.7904x over previous
//
#include <hip/hip_runtime.h>

// Problem constants
#define NB 2
#define CC 512
#define NN 2304
#define NH 8
#define DD 16
#define TT 128          // NH*DD
#define O3 384          // 3*TT
#define NBLK 1152u      // mega-kernel grid size

typedef __attribute__((ext_vector_type(4))) float f32x4;
typedef __attribute__((ext_vector_type(8))) __bf16 bf16x8;
typedef __attribute__((ext_vector_type(4))) __bf16 bf16x4;
typedef __attribute__((ext_vector_type(4))) _Float16 f16x4;

// ---------------------------------------------------------------------------
// Grid barrier, round-10 version. R9's spin polled with ACQUIRE agent loads:
// on multi-XCD gfx950 every ACQUIRE invalidates the per-XCD L2, so 1152
// spinning blocks produced a device-wide invalidate storm (~350us/barrier,
// VALUBusy 0.8%). Fix: RELAXED polling (no cache maintenance per poll),
// RELEASE fetch_add publishes this block's stores (vmcnt drain + L2 wb),
// and exactly ONE __threadfence() per block after the barrier opens.
// Co-residency guaranteed: __launch_bounds__(256,5) -> 5 blocks/CU x 256 CUs
// = 1280 >= 1152. Counters zeroed by hipMemsetAsync before launch.
// ---------------------------------------------------------------------------
__device__ __forceinline__ void gridbar(unsigned* bar, int slot) {
    __syncthreads();
    if (threadIdx.x == 0) {
        __hip_atomic_fetch_add(bar + slot, 1u, __ATOMIC_RELEASE,
                               __HIP_MEMORY_SCOPE_AGENT);
        while (__hip_atomic_load(bar + slot, __ATOMIC_RELAXED,
                                 __HIP_MEMORY_SCOPE_AGENT) < NBLK)
            __builtin_amdgcn_s_sleep(16);
    }
    __syncthreads();
    __threadfence();    // single acquire fence: see producers' flushed stores
}

// ---------------------------------------------------------------------------
// MEGA-KERNEL: all 6 stages (R8-proven bodies) with 5 grid barriers.
// Stage widths: k0=640, k1=864, k2=576 (4 splits x 576 keys), k2c=144,
// k3=1152, k4=512. Idle blocks skip straight to the barrier.
// ---------------------------------------------------------------------------
__global__ __launch_bounds__(256, 5) void mega(
    const float* __restrict__ x, const float* __restrict__ wqkv,
    const float* __restrict__ temp, const float* __restrict__ wout,
    const float* __restrict__ gamma, const float* __restrict__ beta,
    float* out,
    __bf16* __restrict__ xT, __bf16* __restrict__ wqb, __bf16* __restrict__ wob,
    _Float16* __restrict__ Q, _Float16* __restrict__ K, _Float16* __restrict__ VT,
    __bf16* __restrict__ AO, float* __restrict__ Opart, float* __restrict__ Lpart,
    unsigned* bar)
{
    const int bid = blockIdx.x;
    const int t = threadIdx.x;
    const int lane = t & 63, wave = t >> 6;
    const int quad = lane >> 4, col = lane & 15;

    __shared__ float tile[64][65];          // stage 0 (16.6 KB; 5x fits 160KB)
    __shared__ float rs[4], rq[4];          // stage 5

    // ============ stage 0: x transpose fp32->bf16 + weight conversion ======
    if (bid < 576) {
        int b = bid / 288, rem = bid % 288;
        int nt = rem / 8, cb = rem % 8;
        int n0 = nt * 64, c0 = cb * 64;
        int tc = t >> 6, tn = t & 63;
#pragma unroll
        for (int i = 0; i < 16; i++) {
            int cl = i * 4 + tc;
            tile[cl][tn] = x[(size_t)(b * CC + c0 + cl) * NN + n0 + tn];
        }
        __syncthreads();
#pragma unroll
        for (int i = 0; i < 16; i++) {
            int nl = i * 4 + tc;
            xT[(size_t)(b * NN + n0 + nl) * CC + c0 + tn] = (__bf16)tile[tn][nl];
        }
    } else if (bid < 640) {
        int wid = bid - 576;
        int base = wid * 256 + t;
#pragma unroll
        for (int i = 0; i < 16; i++) {
            int j = base + i * 16384;
            if (j < O3 * CC) wqb[j] = (__bf16)wqkv[j];
            else             wob[j - O3 * CC] = (__bf16)wout[j - O3 * CC];
        }
    }
    gridbar(bar, 0);

    // ============ stage 1: QKV GEMM + fused L2 norm (fp16 out) =============
    if (bid < 864) {
        int ob = bid % 12, nt = (bid / 12) % 36, b = bid / 432;
        int n0 = nt * 64 + wave * 16;
        int o0 = ob * 32;

        f32x4 acc0 = {0.f,0.f,0.f,0.f}, acc1 = {0.f,0.f,0.f,0.f};
        const __bf16* arow  = xT + (size_t)(b * NN + n0 + col) * CC + quad * 8;
        const __bf16* brow0 = wqb + (size_t)(o0 + col) * CC + quad * 8;
        const __bf16* brow1 = brow0 + 16 * CC;

        bf16x8 a  = *(const bf16x8*)(arow);
        bf16x8 w0 = *(const bf16x8*)(brow0);
        bf16x8 w1 = *(const bf16x8*)(brow1);
#pragma unroll
        for (int ks = 0; ks < 16; ks++) {
            bf16x8 an, wn0, wn1;
            if (ks < 15) {
                an  = *(const bf16x8*)(arow + (ks + 1) * 32);
                wn0 = *(const bf16x8*)(brow0 + (ks + 1) * 32);
                wn1 = *(const bf16x8*)(brow1 + (ks + 1) * 32);
            }
            acc0 = __builtin_amdgcn_mfma_f32_16x16x32_bf16(a, w0, acc0, 0, 0, 0);
            acc1 = __builtin_amdgcn_mfma_f32_16x16x32_bf16(a, w1, acc1, 0, 0, 0);
            a = an; w0 = wn0; w1 = wn1;
        }
#pragma unroll
        for (int s = 0; s < 2; s++) {
            f32x4 v = s ? acc1 : acc0;
            int oc = o0 + s * 16 + col;
            int d = oc & 15, h = (oc >> 4) & 7, kind = oc >> 7;
            if (kind < 2) {
                float ss0 = v[0]*v[0], ss1 = v[1]*v[1], ss2 = v[2]*v[2], ss3 = v[3]*v[3];
#pragma unroll
                for (int m = 1; m < 16; m <<= 1) {
                    ss0 += __shfl_xor(ss0, m);
                    ss1 += __shfl_xor(ss1, m);
                    ss2 += __shfl_xor(ss2, m);
                    ss3 += __shfl_xor(ss3, m);
                }
                v[0] *= 1.0f / fmaxf(sqrtf(ss0), 1e-12f);
                v[1] *= 1.0f / fmaxf(sqrtf(ss1), 1e-12f);
                v[2] *= 1.0f / fmaxf(sqrtf(ss2), 1e-12f);
                v[3] *= 1.0f / fmaxf(sqrtf(ss3), 1e-12f);
                _Float16* dst = (kind == 0 ? Q : K) + (size_t)(b * NH + h) * NN * DD;
#pragma unroll
                for (int r = 0; r < 4; r++)
                    dst[(size_t)(n0 + quad * 4 + r) * DD + d] = (_Float16)v[r];
            } else {
                f16x4 pk;
#pragma unroll
                for (int r = 0; r < 4; r++) pk[r] = (_Float16)v[r];
                *(f16x4*)(VT + (size_t)((b * NH + h) * DD + d) * NN + n0 + quad * 4) = pk;
            }
        }
    }
    gridbar(bar, 1);

    // ============ stage 2: attention (transpose-free, 4x q-block, split=4) ==
    if (bid < 576) {
        int qt = bid % 9, bh = (bid / 9) % 16, sp = bid / 144;
        int kbase = sp * 576;                // 4 splits x 576 keys = 18 groups of 32
        int qbase = qt * 256 + wave * 64;

        const _Float16* Qb = Q + (size_t)bh * NN * DD;
        float tl2 = temp[bh & 7] * 1.4426950408889634f;

        f16x4 qf0 = *(const f16x4*)(Qb + (size_t)(qbase +  0 + col) * DD + quad * 4);
        f16x4 qf1 = *(const f16x4*)(Qb + (size_t)(qbase + 16 + col) * DD + quad * 4);
        f16x4 qf2 = *(const f16x4*)(Qb + (size_t)(qbase + 32 + col) * DD + quad * 4);
        f16x4 qf3 = *(const f16x4*)(Qb + (size_t)(qbase + 48 + col) * DD + quad * 4);

        f32x4 oa0 = {0.f,0.f,0.f,0.f}, oa1 = {0.f,0.f,0.f,0.f};
        f32x4 oa2 = {0.f,0.f,0.f,0.f}, oa3 = {0.f,0.f,0.f,0.f};
        float la0 = 0.f, la1 = 0.f, la2 = 0.f, la3 = 0.f;
        const f32x4 zc = {0.f,0.f,0.f,0.f};

        const _Float16* kp = K + (size_t)bh * NN * DD + (size_t)(kbase + col) * DD + quad * 4;
        const _Float16* vp = VT + (size_t)bh * DD * NN + (size_t)col * NN + kbase + quad * 4;

        f16x4 kfa = *(const f16x4*)(kp);
        f16x4 kfb = *(const f16x4*)(kp + 16 * DD);
        f16x4 vfa = *(const f16x4*)(vp);
        f16x4 vfb = *(const f16x4*)(vp + 16);

#define K2_CHUNK(KF, VF)                                                        \
    {                                                                           \
        f32x4 s0 = __builtin_amdgcn_mfma_f32_16x16x16f16(KF, qf0, zc, 0, 0, 0); \
        f32x4 s1 = __builtin_amdgcn_mfma_f32_16x16x16f16(KF, qf1, zc, 0, 0, 0); \
        f32x4 s2 = __builtin_amdgcn_mfma_f32_16x16x16f16(KF, qf2, zc, 0, 0, 0); \
        f32x4 s3 = __builtin_amdgcn_mfma_f32_16x16x16f16(KF, qf3, zc, 0, 0, 0); \
        f16x4 p0, p1, p2, p3;                                                   \
        _Pragma("unroll")                                                       \
        for (int r = 0; r < 4; ++r) {                                           \
            float e0 = __builtin_amdgcn_exp2f(tl2 * s0[r]);                     \
            float e1 = __builtin_amdgcn_exp2f(tl2 * s1[r]);                     \
            float e2 = __builtin_amdgcn_exp2f(tl2 * s2[r]);                     \
            float e3 = __builtin_amdgcn_exp2f(tl2 * s3[r]);                     \
            p0[r] = (_Float16)e0; la0 += e0;                                    \
            p1[r] = (_Float16)e1; la1 += e1;                                    \
            p2[r] = (_Float16)e2; la2 += e2;                                    \
            p3[r] = (_Float16)e3; la3 += e3;                                    \
        }                                                                       \
        oa0 = __builtin_amdgcn_mfma_f32_16x16x16f16(VF, p0, oa0, 0, 0, 0);      \
        oa1 = __builtin_amdgcn_mfma_f32_16x16x16f16(VF, p1, oa1, 0, 0, 0);      \
        oa2 = __builtin_amdgcn_mfma_f32_16x16x16f16(VF, p2, oa2, 0, 0, 0);      \
        oa3 = __builtin_amdgcn_mfma_f32_16x16x16f16(VF, p3, oa3, 0, 0, 0);      \
    }

        for (int g = 0; g < 18; ++g) {       // 18 groups x 32 keys = 576
            f16x4 kna, knb, vna, vnb;
            if (g < 17) {
                kna = *(const f16x4*)(kp + 32 * DD);
                knb = *(const f16x4*)(kp + 48 * DD);
                vna = *(const f16x4*)(vp + 32);
                vnb = *(const f16x4*)(vp + 48);
            }
            K2_CHUNK(kfa, vfa)
            K2_CHUNK(kfb, vfb)
            kfa = kna; kfb = knb; vfa = vna; vfb = vnb;
            kp += 32 * DD; vp += 32;
        }
#undef K2_CHUNK

        la0 += __shfl_xor(la0, 16); la0 += __shfl_xor(la0, 32);
        la1 += __shfl_xor(la1, 16); la1 += __shfl_xor(la1, 32);
        la2 += __shfl_xor(la2, 16); la2 += __shfl_xor(la2, 32);
        la3 += __shfl_xor(la3, 16); la3 += __shfl_xor(la3, 32);

        float* Ob = Opart + (((size_t)sp * 16 + bh) * DD + quad * 4) * NN + qbase + col;
#pragma unroll
        for (int r = 0; r < 4; ++r) {
            Ob[(size_t)r * NN +  0] = oa0[r];
            Ob[(size_t)r * NN + 16] = oa1[r];
            Ob[(size_t)r * NN + 32] = oa2[r];
            Ob[(size_t)r * NN + 48] = oa3[r];
        }
        float lv = (quad == 0) ? la0 : (quad == 1) ? la1 : (quad == 2) ? la2 : la3;
        Lpart[((size_t)sp * 16 + bh) * NN + qbase + quad * 16 + col] = lv;
    }
    gridbar(bar, 2);

    // ============ stage 3: combine 4 splits + divide -> AO ==================
    if (bid < 144) {
        int gid = bid * 256 + t;             // 0..36863
        int bh = gid / NN, n = gid % NN;
        int b = bh >> 3, h = bh & 7;
        float l = 0.f;
#pragma unroll
        for (int sp = 0; sp < 4; sp++)
            l += Lpart[((size_t)sp * 16 + bh) * NN + n];
        float inv = 1.0f / l;
        float o[16];
#pragma unroll
        for (int d = 0; d < 16; d++) o[d] = 0.f;
#pragma unroll
        for (int sp = 0; sp < 4; sp++) {
            const float* Ob = Opart + ((size_t)sp * 16 + bh) * DD * NN + n;
#pragma unroll
            for (int d = 0; d < 16; d++) o[d] += Ob[(size_t)d * NN];
        }
        bf16x8 v0, v1;
#pragma unroll
        for (int d = 0; d < 8; d++) v0[d] = (__bf16)(o[d] * inv);
#pragma unroll
        for (int d = 0; d < 8; d++) v1[d] = (__bf16)(o[d + 8] * inv);
        __bf16* dst = AO + (size_t)b * NN * TT + (size_t)n * TT + h * DD;
        *(bf16x8*)dst = v0;
        *(bf16x8*)(dst + 8) = v1;
    }
    gridbar(bar, 3);

    // ============ stage 4: projection -> pre-BN fp32 in d_out ==============
    {
        int cb = bid % 16, nt = (bid / 16) % 36, b = bid / 576;
        int n0 = nt * 64 + wave * 16, c0 = cb * 32;

        f32x4 acc0 = {0.f,0.f,0.f,0.f}, acc1 = {0.f,0.f,0.f,0.f};
        const __bf16* ab  = AO + (size_t)(b * NN + n0 + col) * TT + quad * 8;
        const __bf16* wb0 = wob + (size_t)(c0 + col) * TT + quad * 8;
        const __bf16* wb1 = wb0 + 16 * TT;
#pragma unroll
        for (int ks = 0; ks < 4; ks++) {
            bf16x8 a  = *(const bf16x8*)(ab + ks * 32);
            bf16x8 w0 = *(const bf16x8*)(wb0 + ks * 32);
            bf16x8 w1 = *(const bf16x8*)(wb1 + ks * 32);
            acc0 = __builtin_amdgcn_mfma_f32_16x16x32_bf16(a, w0, acc0, 0, 0, 0);
            acc1 = __builtin_amdgcn_mfma_f32_16x16x32_bf16(a, w1, acc1, 0, 0, 0);
        }
#pragma unroll
        for (int s = 0; s < 2; s++) {
            int c = c0 + s * 16 + col;
            float* dst = out + (size_t)(b * CC + c) * NN + n0 + quad * 4;
            *(f32x4*)dst = s ? acc1 : acc0;
        }
    }
    gridbar(bar, 4);

    // ============ stage 5: training-mode BatchNorm in place =================
    if (bid < 512) {
        int c = bid;
        float vals[18];
        float s = 0.f, q = 0.f;
#pragma unroll
        for (int i = 0; i < 18; i++) {
            int j = i * 256 + t;
            int b = j / NN, n = j % NN;
            float v = out[(size_t)(b * CC + c) * NN + n];
            vals[i] = v; s += v; q += v * v;
        }
#pragma unroll
        for (int m = 1; m < 64; m <<= 1) { s += __shfl_xor(s, m); q += __shfl_xor(q, m); }
        if (lane == 0) { rs[wave] = s; rq[wave] = q; }
        __syncthreads();
        s = rs[0] + rs[1] + rs[2] + rs[3];
        q = rq[0] + rq[1] + rq[2] + rq[3];
        float mean = s * (1.0f / 4608.0f);
        float var = q * (1.0f / 4608.0f) - mean * mean;
        float sc = rsqrtf(var + 1e-5f) * gamma[c];
        float sh = beta[c] - mean * sc;
#pragma unroll
        for (int i = 0; i < 18; i++) {
            int j = i * 256 + t;
            int b = j / NN, n = j % NN;
            out[(size_t)(b * CC + c) * NN + n] = vals[i] * sc + sh;
        }
    }
}

// ---------------------------------------------------------------------------
extern "C" void kernel_launch(void* const* d_in, const int* in_sizes, int n_in,
                              void* d_out, int out_size, void* d_ws, size_t ws_size,
                              hipStream_t stream) {
    const float* x     = (const float*)d_in[0];
    const float* wqkv  = (const float*)d_in[1];
    const float* temp  = (const float*)d_in[2];
    const float* wout  = (const float*)d_in[3];
    const float* gamma = (const float*)d_in[4];
    const float* beta  = (const float*)d_in[5];
    float* out = (float*)d_out;

    char* ws = (char*)d_ws;
    const size_t OFF_XT  = 0;                 // 2*2304*512*2   = 4,718,592
    const size_t OFF_WQ  = 4718592;           // 384*512*2      =   393,216
    const size_t OFF_WO  = 5111808;           // 512*128*2      =   131,072
    const size_t OFF_Q   = 5242880;           // 2*8*2304*16*2  = 1,179,648
    const size_t OFF_K   = 6422528;
    const size_t OFF_VT  = 7602176;
    const size_t OFF_AO  = 8781824;           // 2*2304*128*2   = 1,179,648 -> 9,961,472
    const size_t OFF_OP  = 9961472;           // 4*16*16*2304*4 = 9,437,184 -> 19,398,656
    const size_t OFF_LP  = 19398656;          // 4*16*2304*4    =   589,824 -> 19,988,480
    const size_t OFF_BAR = 19988480;          // 64 B barrier counters

    __bf16* xT  = (__bf16*)(ws + OFF_XT);
    __bf16* wqb = (__bf16*)(ws + OFF_WQ);
    __bf16* wob = (__bf16*)(ws + OFF_WO);
    _Float16* Q  = (_Float16*)(ws + OFF_Q);
    _Float16* K  = (_Float16*)(ws + OFF_K);
    _Float16* VT = (_Float16*)(ws + OFF_VT);
    __bf16* AO  = (__bf16*)(ws + OFF_AO);
    float* Opart = (float*)(ws + OFF_OP);
    float* Lpart = (float*)(ws + OFF_LP);
    unsigned* bar = (unsigned*)(ws + OFF_BAR);

    hipMemsetAsync(ws + OFF_BAR, 0, 64, stream);   // zero barrier counters
    mega<<<NBLK, 256, 0, stream>>>(x, wqkv, temp, wout, gamma, beta, out,
                                   xT, wqb, wob, Q, K, VT, AO, Opart, Lpart, bar);
}

// Round 11
// 149.196 us; speedup vs baseline: 11.8887x; 6.6403x over previous
//
#include <hip/hip_runtime.h>

// Problem constants
#define NB 2
#define CC 512
#define NN 2304
#define NH 8
#define DD 16
#define TT 128          // NH*DD
#define O3 384          // 3*TT

typedef __attribute__((ext_vector_type(4))) float f32x4;
typedef __attribute__((ext_vector_type(8))) __bf16 bf16x8;
typedef __attribute__((ext_vector_type(4))) _Float16 f16x4;

// convert 8 consecutive fp32 -> bf16x8 (two dwordx4 loads + packed cvt)
static __device__ __forceinline__ bf16x8 cvt8(const float* __restrict__ p) {
    f32x4 lo = *(const f32x4*)p;
    f32x4 hi = *(const f32x4*)(p + 4);
    bf16x8 r;
#pragma unroll
    for (int i = 0; i < 4; i++) { r[i] = (__bf16)lo[i]; r[4 + i] = (__bf16)hi[i]; }
    return r;
}

// ---------------------------------------------------------------------------
// Kernel 1 (R11 rewrite): QKV GEMM straight from fp32 x and w_qkv.
//   C[o][n] formulation: A-frag = W[o=lane&15][c] (fp32 32B + cvt),
//   B-frag = x[c][n=lane&15] (8 stride-NN scalar loads + cvt).
//   C-layout: o = o0+s*16+quad*4+r, n = n0+col -> L2-norm over d is an
//   in-lane sum + shfl_xor(16,32); Q/K stores are contiguous f16x4.
// Outputs: Q,K: [bh][n][16] f16 ; VT: [bh][16][n] f16   (same as R8)
// Grid (12,36,2) = 864 blocks; kind (q/k/v) uniform per ob since 32|128.
// ---------------------------------------------------------------------------
__global__ __launch_bounds__(256) void k1_qkv(
    const float* __restrict__ x, const float* __restrict__ wqkv,
    _Float16* __restrict__ Q, _Float16* __restrict__ K, _Float16* __restrict__ VT)
{
    int ob = blockIdx.x, nt = blockIdx.y, b = blockIdx.z;
    int lane = threadIdx.x & 63, wave = threadIdx.x >> 6;
    int quad = lane >> 4, col = lane & 15;
    int n0 = nt * 64 + wave * 16;
    int o0 = ob * 32;

    f32x4 acc0 = {0.f,0.f,0.f,0.f}, acc1 = {0.f,0.f,0.f,0.f};

    const float* wr0 = wqkv + (size_t)(o0 + col) * CC + quad * 8;
    const float* wr1 = wr0 + 16 * CC;
    const float* xb  = x + (size_t)b * CC * NN + (size_t)(quad * 8) * NN + n0 + col;

#pragma unroll 4
    for (int ks = 0; ks < 16; ks++) {
        const float* xc = xb + (size_t)(ks * 32) * NN;
        bf16x8 bb;
        bb[0] = (__bf16)xc[0];
        bb[1] = (__bf16)xc[NN];
        bb[2] = (__bf16)xc[2 * NN];
        bb[3] = (__bf16)xc[3 * NN];
        bb[4] = (__bf16)xc[4 * NN];
        bb[5] = (__bf16)xc[5 * NN];
        bb[6] = (__bf16)xc[6 * NN];
        bb[7] = (__bf16)xc[7 * NN];
        bf16x8 w0 = cvt8(wr0 + ks * 32);
        bf16x8 w1 = cvt8(wr1 + ks * 32);
        acc0 = __builtin_amdgcn_mfma_f32_16x16x32_bf16(w0, bb, acc0, 0, 0, 0);
        acc1 = __builtin_amdgcn_mfma_f32_16x16x32_bf16(w1, bb, acc1, 0, 0, 0);
    }

    int kind = o0 >> 7;                       // 0=q 1=k 2=v, uniform per block
#pragma unroll
    for (int s = 0; s < 2; s++) {
        f32x4 v = s ? acc1 : acc0;
        int h = ((o0 + s * 16) >> 4) & 7;
        int bh = b * NH + h;
        if (kind < 2) {
            float ss = v[0]*v[0] + v[1]*v[1] + v[2]*v[2] + v[3]*v[3];
            ss += __shfl_xor(ss, 16);
            ss += __shfl_xor(ss, 32);
            float inv = 1.0f / fmaxf(sqrtf(ss), 1e-12f);
            f16x4 pk;
#pragma unroll
            for (int r = 0; r < 4; r++) pk[r] = (_Float16)(v[r] * inv);
            _Float16* dst = (kind == 0 ? Q : K)
                          + ((size_t)bh * NN + n0 + col) * DD + quad * 4;
            *(f16x4*)dst = pk;
        } else {
#pragma unroll
            for (int r = 0; r < 4; r++)
                VT[((size_t)bh * DD + quad * 4 + r) * NN + n0 + col] = (_Float16)v[r];
        }
    }
}

// ---------------------------------------------------------------------------
// Kernel 2 (byte-identical to R8): transpose-free flash via K=16 MFMAs,
// 4x register Q-blocking (64 q-rows/wave), 8-way split-K, direct stores.
// Outputs: Opart[sp][bh][d][n] fp32 ; Lpart[sp][bh][n] fp32
// ---------------------------------------------------------------------------
__global__ __launch_bounds__(256) void k2_attn(
    const _Float16* __restrict__ Q, const _Float16* __restrict__ K,
    const _Float16* __restrict__ VT, const float* __restrict__ temp,
    float* __restrict__ Opart, float* __restrict__ Lpart)
{
    int qt = blockIdx.x, bh = blockIdx.y, sp = blockIdx.z;
    int lane = threadIdx.x & 63, wave = threadIdx.x >> 6;
    int quad = lane >> 4, col = lane & 15;
    int kbase = sp * 288;                 // 8 splits x 288 keys
    int qbase = qt * 256 + wave * 64;     // this wave's 64 q-rows

    const _Float16* Qb = Q + (size_t)bh * NN * DD;
    float tl2 = temp[bh & 7] * 1.4426950408889634f;   // exp(x)=2^(x*log2e)

    f16x4 qf0 = *(const f16x4*)(Qb + (size_t)(qbase +  0 + col) * DD + quad * 4);
    f16x4 qf1 = *(const f16x4*)(Qb + (size_t)(qbase + 16 + col) * DD + quad * 4);
    f16x4 qf2 = *(const f16x4*)(Qb + (size_t)(qbase + 32 + col) * DD + quad * 4);
    f16x4 qf3 = *(const f16x4*)(Qb + (size_t)(qbase + 48 + col) * DD + quad * 4);

    f32x4 oa0 = {0.f,0.f,0.f,0.f}, oa1 = {0.f,0.f,0.f,0.f};
    f32x4 oa2 = {0.f,0.f,0.f,0.f}, oa3 = {0.f,0.f,0.f,0.f};
    float la0 = 0.f, la1 = 0.f, la2 = 0.f, la3 = 0.f;
    const f32x4 zc = {0.f,0.f,0.f,0.f};

    const _Float16* kp = K + (size_t)bh * NN * DD + (size_t)(kbase + col) * DD + quad * 4;
    const _Float16* vp = VT + (size_t)bh * DD * NN + (size_t)col * NN + kbase + quad * 4;

    f16x4 kfa = *(const f16x4*)(kp);
    f16x4 kfb = *(const f16x4*)(kp + 16 * DD);
    f16x4 vfa = *(const f16x4*)(vp);
    f16x4 vfb = *(const f16x4*)(vp + 16);

#define K2_CHUNK(KF, VF)                                                        \
    {                                                                           \
        f32x4 s0 = __builtin_amdgcn_mfma_f32_16x16x16f16(KF, qf0, zc, 0, 0, 0); \
        f32x4 s1 = __builtin_amdgcn_mfma_f32_16x16x16f16(KF, qf1, zc, 0, 0, 0); \
        f32x4 s2 = __builtin_amdgcn_mfma_f32_16x16x16f16(KF, qf2, zc, 0, 0, 0); \
        f32x4 s3 = __builtin_amdgcn_mfma_f32_16x16x16f16(KF, qf3, zc, 0, 0, 0); \
        f16x4 p0, p1, p2, p3;                                                   \
        _Pragma("unroll")                                                       \
        for (int r = 0; r < 4; ++r) {                                           \
            float e0 = __builtin_amdgcn_exp2f(tl2 * s0[r]);                     \
            float e1 = __builtin_amdgcn_exp2f(tl2 * s1[r]);                     \
            float e2 = __builtin_amdgcn_exp2f(tl2 * s2[r]);                     \
            float e3 = __builtin_amdgcn_exp2f(tl2 * s3[r]);                     \
            p0[r] = (_Float16)e0; la0 += e0;                                    \
            p1[r] = (_Float16)e1; la1 += e1;                                    \
            p2[r] = (_Float16)e2; la2 += e2;                                    \
            p3[r] = (_Float16)e3; la3 += e3;                                    \
        }                                                                       \
        oa0 = __builtin_amdgcn_mfma_f32_16x16x16f16(VF, p0, oa0, 0, 0, 0);      \
        oa1 = __builtin_amdgcn_mfma_f32_16x16x16f16(VF, p1, oa1, 0, 0, 0);      \
        oa2 = __builtin_amdgcn_mfma_f32_16x16x16f16(VF, p2, oa2, 0, 0, 0);      \
        oa3 = __builtin_amdgcn_mfma_f32_16x16x16f16(VF, p3, oa3, 0, 0, 0);      \
    }

    for (int g = 0; g < 9; ++g) {        // 9 groups x 32 keys = 288
        f16x4 kna, knb, vna, vnb;
        if (g < 8) {
            kna = *(const f16x4*)(kp + 32 * DD);
            knb = *(const f16x4*)(kp + 48 * DD);
            vna = *(const f16x4*)(vp + 32);
            vnb = *(const f16x4*)(vp + 48);
        }
        K2_CHUNK(kfa, vfa)
        K2_CHUNK(kfb, vfb)
        kfa = kna; kfb = knb; vfa = vna; vfb = vnb;
        kp += 32 * DD; vp += 32;
    }
#undef K2_CHUNK

    la0 += __shfl_xor(la0, 16); la0 += __shfl_xor(la0, 32);
    la1 += __shfl_xor(la1, 16); la1 += __shfl_xor(la1, 32);
    la2 += __shfl_xor(la2, 16); la2 += __shfl_xor(la2, 32);
    la3 += __shfl_xor(la3, 16); la3 += __shfl_xor(la3, 32);

    float* Ob = Opart + (((size_t)sp * 16 + bh) * DD + quad * 4) * NN + qbase + col;
#pragma unroll
    for (int r = 0; r < 4; ++r) {
        Ob[(size_t)r * NN +  0] = oa0[r];
        Ob[(size_t)r * NN + 16] = oa1[r];
        Ob[(size_t)r * NN + 32] = oa2[r];
        Ob[(size_t)r * NN + 48] = oa3[r];
    }
    float lv = (quad == 0) ? la0 : (quad == 1) ? la1 : (quad == 2) ? la2 : la3;
    Lpart[((size_t)sp * 16 + bh) * NN + qbase + quad * 16 + col] = lv;
}

// ---------------------------------------------------------------------------
// Kernel 2c (byte-identical to R8): sum 8 split partials + divide, write AO.
// ---------------------------------------------------------------------------
__global__ __launch_bounds__(256) void k2c_combine(
    const float* __restrict__ Opart, const float* __restrict__ Lpart,
    __bf16* __restrict__ AO)
{
    int gid = blockIdx.x * 256 + threadIdx.x;   // 0..36863
    int bh = gid / NN, n = gid % NN;
    int b = bh >> 3, h = bh & 7;
    float l = 0.f;
#pragma unroll
    for (int sp = 0; sp < 8; sp++)
        l += Lpart[((size_t)sp * 16 + bh) * NN + n];
    float inv = 1.0f / l;
    float o[16];
#pragma unroll
    for (int d = 0; d < 16; d++) o[d] = 0.f;
#pragma unroll
    for (int sp = 0; sp < 8; sp++) {
        const float* Ob = Opart + ((size_t)sp * 16 + bh) * DD * NN + n;
#pragma unroll
        for (int d = 0; d < 16; d++) o[d] += Ob[(size_t)d * NN];
    }
    bf16x8 v0, v1;
#pragma unroll
    for (int d = 0; d < 8; d++) v0[d] = (__bf16)(o[d] * inv);
#pragma unroll
    for (int d = 0; d < 8; d++) v1[d] = (__bf16)(o[d + 8] * inv);
    __bf16* dst = AO + (size_t)b * NN * TT + (size_t)n * TT + h * DD;
    *(bf16x8*)dst = v0;
    *(bf16x8*)(dst + 8) = v1;
}

// ---------------------------------------------------------------------------
// Kernel 3: projection, now reading w_out fp32 directly (cvt in register).
// out[b,c,n] = sum_t w_out[c,t] * AO[b,n,t]; pre-BN fp32 straight to d_out.
// ---------------------------------------------------------------------------
__global__ __launch_bounds__(256) void k3_proj(
    const __bf16* __restrict__ AO, const float* __restrict__ wout,
    float* __restrict__ out)
{
    int cb = blockIdx.x, nt = blockIdx.y, b = blockIdx.z;
    int lane = threadIdx.x & 63, wave = threadIdx.x >> 6;
    int quad = lane >> 4, col = lane & 15;
    int n0 = nt * 64 + wave * 16, c0 = cb * 32;

    f32x4 acc0 = {0.f,0.f,0.f,0.f}, acc1 = {0.f,0.f,0.f,0.f};

    const __bf16* ab = AO + (size_t)(b * NN + n0 + col) * TT + quad * 8;
    const float* wb0 = wout + (size_t)(c0 + col) * TT + quad * 8;
    const float* wb1 = wb0 + 16 * TT;
#pragma unroll
    for (int ks = 0; ks < 4; ks++) {
        bf16x8 a  = *(const bf16x8*)(ab + ks * 32);
        bf16x8 w0 = cvt8(wb0 + ks * 32);
        bf16x8 w1 = cvt8(wb1 + ks * 32);
        acc0 = __builtin_amdgcn_mfma_f32_16x16x32_bf16(a, w0, acc0, 0, 0, 0);
        acc1 = __builtin_amdgcn_mfma_f32_16x16x32_bf16(a, w1, acc1, 0, 0, 0);
    }
#pragma unroll
    for (int s = 0; s < 2; s++) {
        int c = c0 + s * 16 + col;
        float* dst = out + (size_t)(b * CC + c) * NN + n0 + quad * 4;
        *(f32x4*)dst = s ? acc1 : acc0;
    }
}

// ---------------------------------------------------------------------------
// Kernel 4 (byte-identical to R8): training-mode BatchNorm in place.
// ---------------------------------------------------------------------------
__global__ __launch_bounds__(256) void k4_bn(
    float* __restrict__ out, const float* __restrict__ gamma,
    const float* __restrict__ beta)
{
    int c = blockIdx.x;
    int t = threadIdx.x;
    float vals[18];
    float s = 0.f, q = 0.f;
#pragma unroll
    for (int i = 0; i < 18; i++) {
        int j = i * 256 + t;          // 0..4607 over (b,n)
        int b = j / NN, n = j % NN;
        float v = out[(size_t)(b * CC + c) * NN + n];
        vals[i] = v; s += v; q += v * v;
    }
#pragma unroll
    for (int m = 1; m < 64; m <<= 1) { s += __shfl_xor(s, m); q += __shfl_xor(q, m); }
    __shared__ float rs[4], rq[4];
    int lane = t & 63, wave = t >> 6;
    if (lane == 0) { rs[wave] = s; rq[wave] = q; }
    __syncthreads();
    s = rs[0] + rs[1] + rs[2] + rs[3];
    q = rq[0] + rq[1] + rq[2] + rq[3];
    float mean = s * (1.0f / 4608.0f);
    float var = q * (1.0f / 4608.0f) - mean * mean;
    float sc = rsqrtf(var + 1e-5f) * gamma[c];
    float sh = beta[c] - mean * sc;
#pragma unroll
    for (int i = 0; i < 18; i++) {
        int j = i * 256 + t;
        int b = j / NN, n = j % NN;
        out[(size_t)(b * CC + c) * NN + n] = vals[i] * sc + sh;
    }
}

// ---------------------------------------------------------------------------
extern "C" void kernel_launch(void* const* d_in, const int* in_sizes, int n_in,
                              void* d_out, int out_size, void* d_ws, size_t ws_size,
                              hipStream_t stream) {
    const float* x     = (const float*)d_in[0];
    const float* wqkv  = (const float*)d_in[1];
    const float* temp  = (const float*)d_in[2];
    const float* wout  = (const float*)d_in[3];
    const float* gamma = (const float*)d_in[4];
    const float* beta  = (const float*)d_in[5];
    float* out = (float*)d_out;

    char* ws = (char*)d_ws;
    // workspace layout (bytes) — no staging buffers left, only Q/K/VT/AO and
    // the split-K partials.
    const size_t OFF_Q  = 0;                  // 2*8*2304*16*2  = 1,179,648
    const size_t OFF_K  = 1179648;
    const size_t OFF_VT = 2359296;
    const size_t OFF_AO = 3538944;            // 2*2304*128*2   = 1,179,648 -> 4,718,592
    const size_t OFF_OP = 4718592;            // 8*16*16*2304*4 = 18,874,368 -> 23,592,960
    const size_t OFF_LP = 23592960;           // 8*16*2304*4    = 1,179,648 -> 24,772,608

    _Float16* Q  = (_Float16*)(ws + OFF_Q);
    _Float16* K  = (_Float16*)(ws + OFF_K);
    _Float16* VT = (_Float16*)(ws + OFF_VT);
    __bf16* AO   = (__bf16*)(ws + OFF_AO);
    float* Opart = (float*)(ws + OFF_OP);
    float* Lpart = (float*)(ws + OFF_LP);

    k1_qkv<<<dim3(12, 36, 2), 256, 0, stream>>>(x, wqkv, Q, K, VT);
    k2_attn<<<dim3(9, 16, 8), 256, 0, stream>>>(Q, K, VT, temp, Opart, Lpart);
    k2c_combine<<<144, 256, 0, stream>>>(Opart, Lpart, AO);
    k3_proj<<<dim3(16, 36, 2), 256, 0, stream>>>(AO, wout, out);
    k4_bn<<<512, 256, 0, stream>>>(out, gamma, beta);
}

// Round 13
// 142.632 us; speedup vs baseline: 12.4358x; 1.0460x over previous
//
#include <hip/hip_runtime.h>

// Problem constants
#define NB 2
#define CC 512
#define NN 2304
#define NH 8
#define DD 16
#define TT 128          // NH*DD
#define O3 384          // 3*TT

typedef __attribute__((ext_vector_type(4))) float f32x4;
typedef __attribute__((ext_vector_type(8))) __bf16 bf16x8;
typedef __attribute__((ext_vector_type(4))) __bf16 bf16x4;
typedef __attribute__((ext_vector_type(4))) _Float16 f16x4;

// ---------------------------------------------------------------------------
// Kernel 0 (R8): convert x [b,c,n] fp32 -> xT [b,n,c] bf16 (LDS transpose),
//                plus fp32->bf16 conversion of w_qkv and w_out.
// ---------------------------------------------------------------------------
__global__ __launch_bounds__(256) void k0_convert(
    const float* __restrict__ x, const float* __restrict__ wqkv,
    const float* __restrict__ wout,
    __bf16* __restrict__ xT, __bf16* __restrict__ wqb, __bf16* __restrict__ wob)
{
    int bid = blockIdx.x;
    int t = threadIdx.x;
    if (bid < 576) {
        __shared__ float tile[64][65];
        int b = bid / 288, rem = bid % 288;
        int nt = rem / 8, cb = rem % 8;
        int n0 = nt * 64, c0 = cb * 64;
        int tc = t >> 6, tn = t & 63;
#pragma unroll
        for (int i = 0; i < 16; i++) {
            int cl = i * 4 + tc;
            tile[cl][tn] = x[(size_t)(b * CC + c0 + cl) * NN + n0 + tn];
        }
        __syncthreads();
#pragma unroll
        for (int i = 0; i < 16; i++) {
            int nl = i * 4 + tc;
            xT[(size_t)(b * NN + n0 + nl) * CC + c0 + tn] = (__bf16)tile[tn][nl];
        }
    } else {
        int wid = bid - 576;
        int base = wid * 256 + t;
#pragma unroll
        for (int i = 0; i < 16; i++) {
            int j = base + i * 16384;           // covers 262144 = 384*512 + 512*128
            if (j < O3 * CC) wqb[j] = (__bf16)wqkv[j];
            else             wob[j - O3 * CC] = (__bf16)wout[j - O3 * CC];
        }
    }
}

// ---------------------------------------------------------------------------
// Kernel 1 (R8): QKV GEMM + fused per-head L2 norm. Outputs fp16:
//   Q,K: [bh][n][16] f16 ; VT: [bh][16][n] f16
// ---------------------------------------------------------------------------
__global__ __launch_bounds__(256) void k1_qkv(
    const __bf16* __restrict__ xT, const __bf16* __restrict__ wqb,
    _Float16* __restrict__ Q, _Float16* __restrict__ K, _Float16* __restrict__ VT)
{
    int ob = blockIdx.x, nt = blockIdx.y, b = blockIdx.z;
    int lane = threadIdx.x & 63, wave = threadIdx.x >> 6;
    int quad = lane >> 4, col = lane & 15;
    int n0 = nt * 64 + wave * 16;
    int o0 = ob * 32;

    f32x4 acc0 = {0.f,0.f,0.f,0.f}, acc1 = {0.f,0.f,0.f,0.f};
    const __bf16* arow  = xT + (size_t)(b * NN + n0 + col) * CC + quad * 8;
    const __bf16* brow0 = wqb + (size_t)(o0 + col) * CC + quad * 8;
    const __bf16* brow1 = brow0 + 16 * CC;

    bf16x8 a  = *(const bf16x8*)(arow);
    bf16x8 w0 = *(const bf16x8*)(brow0);
    bf16x8 w1 = *(const bf16x8*)(brow1);
#pragma unroll
    for (int ks = 0; ks < 16; ks++) {
        bf16x8 an, wn0, wn1;
        if (ks < 15) {
            an  = *(const bf16x8*)(arow + (ks + 1) * 32);
            wn0 = *(const bf16x8*)(brow0 + (ks + 1) * 32);
            wn1 = *(const bf16x8*)(brow1 + (ks + 1) * 32);
        }
        acc0 = __builtin_amdgcn_mfma_f32_16x16x32_bf16(a, w0, acc0, 0, 0, 0);
        acc1 = __builtin_amdgcn_mfma_f32_16x16x32_bf16(a, w1, acc1, 0, 0, 0);
        a = an; w0 = wn0; w1 = wn1;
    }

#pragma unroll
    for (int s = 0; s < 2; s++) {
        f32x4 v = s ? acc1 : acc0;
        int oc = o0 + s * 16 + col;
        int d = oc & 15, h = (oc >> 4) & 7, kind = oc >> 7;  // 0=q 1=k 2=v
        if (kind < 2) {
            float ss0 = v[0]*v[0], ss1 = v[1]*v[1], ss2 = v[2]*v[2], ss3 = v[3]*v[3];
#pragma unroll
            for (int m = 1; m < 16; m <<= 1) {
                ss0 += __shfl_xor(ss0, m);
                ss1 += __shfl_xor(ss1, m);
                ss2 += __shfl_xor(ss2, m);
                ss3 += __shfl_xor(ss3, m);
            }
            v[0] *= 1.0f / fmaxf(sqrtf(ss0), 1e-12f);
            v[1] *= 1.0f / fmaxf(sqrtf(ss1), 1e-12f);
            v[2] *= 1.0f / fmaxf(sqrtf(ss2), 1e-12f);
            v[3] *= 1.0f / fmaxf(sqrtf(ss3), 1e-12f);
            _Float16* dst = (kind == 0 ? Q : K) + (size_t)(b * NH + h) * NN * DD;
#pragma unroll
            for (int r = 0; r < 4; r++)
                dst[(size_t)(n0 + quad * 4 + r) * DD + d] = (_Float16)v[r];
        } else {
            f16x4 pk;
#pragma unroll
            for (int r = 0; r < 4; r++) pk[r] = (_Float16)v[r];
            *(f16x4*)(VT + (size_t)((b * NH + h) * DD + d) * NN + n0 + quad * 4) = pk;
        }
    }
}

// ---------------------------------------------------------------------------
// Kernel 2 (R13 = R12 + compile fix): transpose-free flash, 4x q-block,
// 8-way split-K. (1) softmax denominator via extra MFMA against all-ones
// A-fragment on the SAME rounded P fragment -> exact num/den consistency, no
// VALU adds, no epilogue shuffles. (2) packed f32->f16 cvt via cvt_pkrtz
// (returns __fp16x2 -> captured with auto, element-copied). (3) Opart bf16
// in [.][n][d] layout: 4 stores x 8B/lane, 512B contiguous per wave.
// Outputs: Opart[sp*16+bh][n][d] bf16 ; Lpart[sp*16+bh][n] fp32
// ---------------------------------------------------------------------------
__global__ __launch_bounds__(256) void k2_attn(
    const _Float16* __restrict__ Q, const _Float16* __restrict__ K,
    const _Float16* __restrict__ VT, const float* __restrict__ temp,
    __bf16* __restrict__ Opart, float* __restrict__ Lpart)
{
    int qt = blockIdx.x, bh = blockIdx.y, sp = blockIdx.z;
    int lane = threadIdx.x & 63, wave = threadIdx.x >> 6;
    int quad = lane >> 4, col = lane & 15;
    int kbase = sp * 288;                 // 8 splits x 288 keys
    int qbase = qt * 256 + wave * 64;     // this wave's 64 q-rows

    const _Float16* Qb = Q + (size_t)bh * NN * DD;
    float tl2 = temp[bh & 7] * 1.4426950408889634f;   // exp(x)=2^(x*log2e)

    f16x4 qf0 = *(const f16x4*)(Qb + (size_t)(qbase +  0 + col) * DD + quad * 4);
    f16x4 qf1 = *(const f16x4*)(Qb + (size_t)(qbase + 16 + col) * DD + quad * 4);
    f16x4 qf2 = *(const f16x4*)(Qb + (size_t)(qbase + 32 + col) * DD + quad * 4);
    f16x4 qf3 = *(const f16x4*)(Qb + (size_t)(qbase + 48 + col) * DD + quad * 4);

    f32x4 oa0 = {0.f,0.f,0.f,0.f}, oa1 = {0.f,0.f,0.f,0.f};
    f32x4 oa2 = {0.f,0.f,0.f,0.f}, oa3 = {0.f,0.f,0.f,0.f};
    f32x4 la0 = {0.f,0.f,0.f,0.f}, la1 = {0.f,0.f,0.f,0.f};
    f32x4 la2 = {0.f,0.f,0.f,0.f}, la3 = {0.f,0.f,0.f,0.f};
    const f32x4 zc = {0.f,0.f,0.f,0.f};
    f16x4 onef;
#pragma unroll
    for (int i = 0; i < 4; i++) onef[i] = (_Float16)1.0f;

    const _Float16* kp = K + (size_t)bh * NN * DD + (size_t)(kbase + col) * DD + quad * 4;
    const _Float16* vp = VT + (size_t)bh * DD * NN + (size_t)col * NN + kbase + quad * 4;

    f16x4 kfa = *(const f16x4*)(kp);
    f16x4 kfb = *(const f16x4*)(kp + 16 * DD);
    f16x4 vfa = *(const f16x4*)(vp);
    f16x4 vfb = *(const f16x4*)(vp + 16);

#define K2_EXPP(SF, PF)                                                         \
    {                                                                           \
        float e0 = __builtin_amdgcn_exp2f(tl2 * SF[0]);                         \
        float e1 = __builtin_amdgcn_exp2f(tl2 * SF[1]);                         \
        float e2 = __builtin_amdgcn_exp2f(tl2 * SF[2]);                         \
        float e3 = __builtin_amdgcn_exp2f(tl2 * SF[3]);                         \
        auto lo = __builtin_amdgcn_cvt_pkrtz(e0, e1);                           \
        auto hi = __builtin_amdgcn_cvt_pkrtz(e2, e3);                           \
        PF[0] = (_Float16)lo[0]; PF[1] = (_Float16)lo[1];                       \
        PF[2] = (_Float16)hi[0]; PF[3] = (_Float16)hi[1];                       \
    }

#define K2_CHUNK(KF, VF)                                                        \
    {                                                                           \
        f32x4 s0 = __builtin_amdgcn_mfma_f32_16x16x16f16(KF, qf0, zc, 0, 0, 0); \
        f32x4 s1 = __builtin_amdgcn_mfma_f32_16x16x16f16(KF, qf1, zc, 0, 0, 0); \
        f32x4 s2 = __builtin_amdgcn_mfma_f32_16x16x16f16(KF, qf2, zc, 0, 0, 0); \
        f32x4 s3 = __builtin_amdgcn_mfma_f32_16x16x16f16(KF, qf3, zc, 0, 0, 0); \
        f16x4 p0, p1, p2, p3;                                                   \
        K2_EXPP(s0, p0) K2_EXPP(s1, p1) K2_EXPP(s2, p2) K2_EXPP(s3, p3)         \
        oa0 = __builtin_amdgcn_mfma_f32_16x16x16f16(VF, p0, oa0, 0, 0, 0);      \
        oa1 = __builtin_amdgcn_mfma_f32_16x16x16f16(VF, p1, oa1, 0, 0, 0);      \
        oa2 = __builtin_amdgcn_mfma_f32_16x16x16f16(VF, p2, oa2, 0, 0, 0);      \
        oa3 = __builtin_amdgcn_mfma_f32_16x16x16f16(VF, p3, oa3, 0, 0, 0);      \
        la0 = __builtin_amdgcn_mfma_f32_16x16x16f16(onef, p0, la0, 0, 0, 0);    \
        la1 = __builtin_amdgcn_mfma_f32_16x16x16f16(onef, p1, la1, 0, 0, 0);    \
        la2 = __builtin_amdgcn_mfma_f32_16x16x16f16(onef, p2, la2, 0, 0, 0);    \
        la3 = __builtin_amdgcn_mfma_f32_16x16x16f16(onef, p3, la3, 0, 0, 0);    \
    }

    for (int g = 0; g < 9; ++g) {        // 9 groups x 32 keys = 288
        f16x4 kna, knb, vna, vnb;
        if (g < 8) {
            kna = *(const f16x4*)(kp + 32 * DD);
            knb = *(const f16x4*)(kp + 48 * DD);
            vna = *(const f16x4*)(vp + 32);
            vnb = *(const f16x4*)(vp + 48);
        }
        K2_CHUNK(kfa, vfa)
        K2_CHUNK(kfb, vfb)
        kfa = kna; kfb = knb; vfa = vna; vfb = vnb;
        kp += 32 * DD; vp += 32;
    }
#undef K2_CHUNK
#undef K2_EXPP

    // Opart[sb][n][d] bf16: lane(quad,col) stores d=quad*4..+3 for n=...+f*16+col
    // -> 8B/lane, 64 lanes contiguous (512B per store).
    __bf16* Ob = Opart + (((size_t)sp * 16 + bh) * NN + qbase) * DD + (size_t)col * DD + quad * 4;
    bf16x4 w0, w1, w2, w3;
#pragma unroll
    for (int r = 0; r < 4; ++r) {
        w0[r] = (__bf16)oa0[r]; w1[r] = (__bf16)oa1[r];
        w2[r] = (__bf16)oa2[r]; w3[r] = (__bf16)oa3[r];
    }
    *(bf16x4*)(Ob)               = w0;
    *(bf16x4*)(Ob + 16 * DD)     = w1;
    *(bf16x4*)(Ob + 32 * DD)     = w2;
    *(bf16x4*)(Ob + 48 * DD)     = w3;

    // every lane holds l[q=col] in la_f (all 4 regs equal); lane's quad picks frag
    float lv = (quad == 0) ? la0[0] : (quad == 1) ? la1[0] : (quad == 2) ? la2[0] : la3[0];
    Lpart[((size_t)sp * 16 + bh) * NN + qbase + quad * 16 + col] = lv;
}

// ---------------------------------------------------------------------------
// Kernel 2c (R12): sum 8 bf16 split partials + divide, write AO.
// Opart[sb][n][d]: per (bh,n) each split is 32B contiguous -> 2 bf16x8 loads.
// ---------------------------------------------------------------------------
__global__ __launch_bounds__(256) void k2c_combine(
    const __bf16* __restrict__ Opart, const float* __restrict__ Lpart,
    __bf16* __restrict__ AO)
{
    int gid = blockIdx.x * 256 + threadIdx.x;   // 0..36863
    int bh = gid / NN, n = gid % NN;
    int b = bh >> 3, h = bh & 7;
    float l = 0.f;
#pragma unroll
    for (int sp = 0; sp < 8; sp++)
        l += Lpart[((size_t)sp * 16 + bh) * NN + n];
    float inv = 1.0f / l;
    float o[16];
#pragma unroll
    for (int d = 0; d < 16; d++) o[d] = 0.f;
#pragma unroll
    for (int sp = 0; sp < 8; sp++) {
        const __bf16* Ob = Opart + (((size_t)sp * 16 + bh) * NN + n) * DD;
        bf16x8 lo = *(const bf16x8*)(Ob);
        bf16x8 hi = *(const bf16x8*)(Ob + 8);
#pragma unroll
        for (int d = 0; d < 8; d++) { o[d] += (float)lo[d]; o[d + 8] += (float)hi[d]; }
    }
    bf16x8 v0, v1;
#pragma unroll
    for (int d = 0; d < 8; d++) v0[d] = (__bf16)(o[d] * inv);
#pragma unroll
    for (int d = 0; d < 8; d++) v1[d] = (__bf16)(o[d + 8] * inv);
    __bf16* dst = AO + (size_t)b * NN * TT + (size_t)n * TT + h * DD;
    *(bf16x8*)dst = v0;
    *(bf16x8*)(dst + 8) = v1;
}

// ---------------------------------------------------------------------------
// Kernel 3 (R8): projection -> pre-BN fp32 straight into d_out.
// ---------------------------------------------------------------------------
__global__ __launch_bounds__(256) void k3_proj(
    const __bf16* __restrict__ AO, const __bf16* __restrict__ wob,
    float* __restrict__ out)
{
    int cb = blockIdx.x, nt = blockIdx.y, b = blockIdx.z;
    int lane = threadIdx.x & 63, wave = threadIdx.x >> 6;
    int quad = lane >> 4, col = lane & 15;
    int n0 = nt * 64 + wave * 16, c0 = cb * 32;

    f32x4 acc0 = {0.f,0.f,0.f,0.f}, acc1 = {0.f,0.f,0.f,0.f};
    const __bf16* ab  = AO + (size_t)(b * NN + n0 + col) * TT + quad * 8;
    const __bf16* wb0 = wob + (size_t)(c0 + col) * TT + quad * 8;
    const __bf16* wb1 = wb0 + 16 * TT;
#pragma unroll
    for (int ks = 0; ks < 4; ks++) {
        bf16x8 a  = *(const bf16x8*)(ab + ks * 32);
        bf16x8 w0 = *(const bf16x8*)(wb0 + ks * 32);
        bf16x8 w1 = *(const bf16x8*)(wb1 + ks * 32);
        acc0 = __builtin_amdgcn_mfma_f32_16x16x32_bf16(a, w0, acc0, 0, 0, 0);
        acc1 = __builtin_amdgcn_mfma_f32_16x16x32_bf16(a, w1, acc1, 0, 0, 0);
    }
#pragma unroll
    for (int s = 0; s < 2; s++) {
        int c = c0 + s * 16 + col;
        float* dst = out + (size_t)(b * CC + c) * NN + n0 + quad * 4;
        *(f32x4*)dst = s ? acc1 : acc0;
    }
}

// ---------------------------------------------------------------------------
// Kernel 4 (R8): training-mode BatchNorm, in place on d_out.
// ---------------------------------------------------------------------------
__global__ __launch_bounds__(256) void k4_bn(
    float* __restrict__ out, const float* __restrict__ gamma,
    const float* __restrict__ beta)
{
    int c = blockIdx.x;
    int t = threadIdx.x;
    float vals[18];
    float s = 0.f, q = 0.f;
#pragma unroll
    for (int i = 0; i < 18; i++) {
        int j = i * 256 + t;          // 0..4607 over (b,n)
        int b = j / NN, n = j % NN;
        float v = out[(size_t)(b * CC + c) * NN + n];
        vals[i] = v; s += v; q += v * v;
    }
#pragma unroll
    for (int m = 1; m < 64; m <<= 1) { s += __shfl_xor(s, m); q += __shfl_xor(q, m); }
    __shared__ float rs[4], rq[4];
    int lane = t & 63, wave = t >> 6;
    if (lane == 0) { rs[wave] = s; rq[wave] = q; }
    __syncthreads();
    s = rs[0] + rs[1] + rs[2] + rs[3];
    q = rq[0] + rq[1] + rq[2] + rq[3];
    float mean = s * (1.0f / 4608.0f);
    float var = q * (1.0f / 4608.0f) - mean * mean;
    float sc = rsqrtf(var + 1e-5f) * gamma[c];
    float sh = beta[c] - mean * sc;
#pragma unroll
    for (int i = 0; i < 18; i++) {
        int j = i * 256 + t;
        int b = j / NN, n = j % NN;
        out[(size_t)(b * CC + c) * NN + n] = vals[i] * sc + sh;
    }
}

// ---------------------------------------------------------------------------
extern "C" void kernel_launch(void* const* d_in, const int* in_sizes, int n_in,
                              void* d_out, int out_size, void* d_ws, size_t ws_size,
                              hipStream_t stream) {
    const float* x     = (const float*)d_in[0];
    const float* wqkv  = (const float*)d_in[1];
    const float* temp  = (const float*)d_in[2];
    const float* wout  = (const float*)d_in[3];
    const float* gamma = (const float*)d_in[4];
    const float* beta  = (const float*)d_in[5];
    float* out = (float*)d_out;

    char* ws = (char*)d_ws;
    const size_t OFF_XT = 0;                 // 2*2304*512*2     = 4,718,592
    const size_t OFF_WQ = 4718592;           // 384*512*2        =   393,216
    const size_t OFF_WO = 5111808;           // 512*128*2        =   131,072
    const size_t OFF_Q  = 5242880;           // 2*8*2304*16*2    = 1,179,648
    const size_t OFF_K  = 6422528;
    const size_t OFF_VT = 7602176;
    const size_t OFF_AO = 8781824;           // 2*2304*128*2     = 1,179,648 -> 9,961,472
    const size_t OFF_OP = 9961472;           // 8*16*2304*16*2   = 9,437,184 -> 19,398,656 (bf16)
    const size_t OFF_LP = 19398656;          // 8*16*2304*4      = 1,179,648 -> 20,578,304

    __bf16* xT  = (__bf16*)(ws + OFF_XT);
    __bf16* wqb = (__bf16*)(ws + OFF_WQ);
    __bf16* wob = (__bf16*)(ws + OFF_WO);
    _Float16* Q  = (_Float16*)(ws + OFF_Q);
    _Float16* K  = (_Float16*)(ws + OFF_K);
    _Float16* VT = (_Float16*)(ws + OFF_VT);
    __bf16* AO   = (__bf16*)(ws + OFF_AO);
    __bf16* Opart = (__bf16*)(ws + OFF_OP);
    float* Lpart  = (float*)(ws + OFF_LP);

    k0_convert<<<640, 256, 0, stream>>>(x, wqkv, wout, xT, wqb, wob);
    k1_qkv<<<dim3(12, 36, 2), 256, 0, stream>>>(xT, wqb, Q, K, VT);
    k2_attn<<<dim3(9, 16, 8), 256, 0, stream>>>(Q, K, VT, temp, Opart, Lpart);
    k2c_combine<<<144, 256, 0, stream>>>(Opart, Lpart, AO);
    k3_proj<<<dim3(16, 36, 2), 256, 0, stream>>>(AO, wob, out);
    k4_bn<<<512, 256, 0, stream>>>(out, gamma, beta);
}